// Round 1
// baseline (295.289 us; speedup 1.0000x reference)
//
#include <hip/hip_runtime.h>
#include <cstdint>
#include <cstddef>

// ---------------- problem constants ----------------
#define B_ 4
#define S_ 4096
#define E_ 512
#define H_ 8
#define D_ 64
#define NPOS 16384      // B*S
#define QKVC 1536       // 3*E
#define K_ 512          // contraction dim of both GEMMs

typedef unsigned short u16;
typedef u16    u16x8  __attribute__((ext_vector_type(8)));
typedef u16    u16x4  __attribute__((ext_vector_type(4)));
typedef __bf16 bf16x8 __attribute__((ext_vector_type(8)));
typedef float  f32x4  __attribute__((ext_vector_type(4)));

__device__ __forceinline__ u16 f2bf(float f) {
    unsigned u = __builtin_bit_cast(unsigned, f);
    unsigned r = (u + 0x7fffu + ((u >> 16) & 1u)) >> 16;   // RNE, finite inputs
    return (u16)r;
}

// ---------------- fp32 -> bf16 conversion (vectorized x4) ----------------
__global__ void cvt_kernel(const float4* __restrict__ in, u16x4* __restrict__ out, int n4) {
    int i = blockIdx.x * 256 + threadIdx.x;
    if (i < n4) {
        float4 v = in[i];
        u16x4 o;
        o[0] = f2bf(v.x); o[1] = f2bf(v.y); o[2] = f2bf(v.z); o[3] = f2bf(v.w);
        out[i] = o;
    }
}

// ---------------- bf16 MFMA GEMM: C[M,N] = A[M,K] @ B[N,K]^T + bias ----------------
// act==1: sigmoid applied to columns with (n % 192) < 128  (q,k channels of qkv)
// 64x64 tile / block (4 waves, each 32x32 = 2x2 MFMA tiles), BK=32, LDS padded stride 40.
__global__ __launch_bounds__(256) void gemm_bt(
        const u16* __restrict__ A, const u16* __restrict__ Bw,
        const float* __restrict__ bias, float* __restrict__ C,
        int M, int N, int K, int act) {
    __shared__ u16 As[64][40];
    __shared__ u16 Bs[64][40];
    const int tid  = threadIdx.x;
    const int m0   = blockIdx.y * 64;
    const int n0   = blockIdx.x * 64;
    const int wave = tid >> 6, lane = tid & 63;
    const int wm = (wave & 1) * 32, wn = (wave >> 1) * 32;
    const int fm = lane & 15, fk = (lane >> 4) * 8;
    const int lrow = tid >> 2, lcol = (tid & 3) * 8;

    f32x4 acc[2][2] = {{{0,0,0,0},{0,0,0,0}},{{0,0,0,0},{0,0,0,0}}};

    const u16* Aptr = A  + (size_t)(m0 + lrow) * K + lcol;
    const u16* Bptr = Bw + (size_t)(n0 + lrow) * K + lcol;

    for (int k0 = 0; k0 < K; k0 += 32) {
        *(u16x8*)(&As[lrow][lcol]) = *(const u16x8*)(Aptr + k0);
        *(u16x8*)(&Bs[lrow][lcol]) = *(const u16x8*)(Bptr + k0);
        __syncthreads();
        bf16x8 a0 = *(const bf16x8*)(&As[wm + fm][fk]);
        bf16x8 a1 = *(const bf16x8*)(&As[wm + 16 + fm][fk]);
        bf16x8 b0 = *(const bf16x8*)(&Bs[wn + fm][fk]);
        bf16x8 b1 = *(const bf16x8*)(&Bs[wn + 16 + fm][fk]);
        acc[0][0] = __builtin_amdgcn_mfma_f32_16x16x32_bf16(a0, b0, acc[0][0], 0, 0, 0);
        acc[0][1] = __builtin_amdgcn_mfma_f32_16x16x32_bf16(a0, b1, acc[0][1], 0, 0, 0);
        acc[1][0] = __builtin_amdgcn_mfma_f32_16x16x32_bf16(a1, b0, acc[1][0], 0, 0, 0);
        acc[1][1] = __builtin_amdgcn_mfma_f32_16x16x32_bf16(a1, b1, acc[1][1], 0, 0, 0);
        __syncthreads();
    }

    // epilogue: C/D layout col = lane&15, row = (lane>>4)*4 + reg   [verified m89/m91]
    const int cn = lane & 15, rb = (lane >> 4) * 4;
    for (int i = 0; i < 2; ++i) {
        int mbase = m0 + wm + i * 16 + rb;
        for (int j = 0; j < 2; ++j) {
            int nn = n0 + wn + j * 16 + cn;
            float bv = bias[nn];
            bool sg = (act != 0) && ((nn % 192) < 128);
            f32x4 a = acc[i][j];
            #pragma unroll
            for (int r = 0; r < 4; ++r) {
                float v = a[r] + bv;
                if (sg) v = 1.f / (1.f + expf(-v));
                C[(size_t)(mbase + r) * N + nn] = v;
            }
        }
    }
}

// ---------------- K2: partial sums over s of q,k  (grid: (32 bh, 16 schunk) x 256) ----------------
__global__ void k2_partial(const float* __restrict__ QKV, float* __restrict__ pq, float* __restrict__ pk) {
    int bh = blockIdx.x, sc = blockIdx.y;
    int b = bh >> 3, h = bh & 7;
    int d = threadIdx.x & 63, sub = threadIdx.x >> 6;
    int s0 = sc * 256 + sub * 64;
    float aq = 0.f, ak = 0.f;
    size_t base = (size_t)b * S_ * QKVC + h * 192 + d;
    for (int s = s0; s < s0 + 64; ++s) {
        const float* p = QKV + base + (size_t)s * QKVC;
        aq += p[0];
        ak += p[64];
    }
    __shared__ float lq[4][64], lk[4][64];
    lq[sub][d] = aq; lk[sub][d] = ak;
    __syncthreads();
    if (threadIdx.x < 64) {
        pq[(bh * 16 + sc) * 64 + d] = lq[0][d] + lq[1][d] + lq[2][d] + lq[3][d];
        pk[(bh * 16 + sc) * 64 + d] = lk[0][d] + lk[1][d] + lk[2][d] + lk[3][d];
    }
}

// ---------------- K2b: fold 16 partials  (grid: 32 x 64) ----------------
__global__ void k2_final(const float* __restrict__ pa, const float* __restrict__ pb,
                         float* __restrict__ oa, float* __restrict__ ob) {
    int bh = blockIdx.x, d = threadIdx.x;
    float aa = 0.f, ab = 0.f;
    for (int c = 0; c < 16; ++c) {
        aa += pa[(bh * 16 + c) * 64 + d];
        ab += pb[(bh * 16 + c) * 64 + d];
    }
    oa[bh * 64 + d] = aa;
    ob[bh * 64 + d] = ab;
}

// ---------------- K3/K5: per-position dots   outA = sum_d q*vecA, outB = sum_d k*vecB ----------------
// grid: NPOS/4 x 256 (wave per position)
__global__ void io_kernel(const float* __restrict__ QKV,
                          const float* __restrict__ vecA, const float* __restrict__ vecB,
                          float* __restrict__ outA, float* __restrict__ outB) {
    int wv = threadIdx.x >> 6, lane = threadIdx.x & 63;
    int p = blockIdx.x * 4 + wv;
    int b = p >> 12;
    size_t base = (size_t)p * QKVC;
    for (int h = 0; h < 8; ++h) {
        float q = QKV[base + h * 192 + lane];
        float k = QKV[base + h * 192 + 64 + lane];
        float vi = q * vecA[(b * 8 + h) * 64 + lane];
        float vo = k * vecB[(b * 8 + h) * 64 + lane];
        #pragma unroll
        for (int off = 32; off > 0; off >>= 1) {
            vi += __shfl_xor(vi, off);
            vo += __shfl_xor(vo, off);
        }
        if (lane == 0) {
            outA[(size_t)p * 8 + h] = vi;
            outB[(size_t)p * 8 + h] = vo;
        }
    }
}

// ---------------- K4: partial sums over s of q/i and k/o ----------------
__global__ void k4_partial(const float* __restrict__ QKV,
                           const float* __restrict__ iv, const float* __restrict__ ov,
                           float* __restrict__ pqi, float* __restrict__ pko) {
    int bh = blockIdx.x, sc = blockIdx.y;
    int b = bh >> 3, h = bh & 7;
    int d = threadIdx.x & 63, sub = threadIdx.x >> 6;
    int s0 = sc * 256 + sub * 64;
    float aqi = 0.f, ako = 0.f;
    for (int s = s0; s < s0 + 64; ++s) {
        size_t pos = (size_t)b * S_ + s;
        float invi = 1.f / iv[pos * 8 + h];
        float invo = 1.f / ov[pos * 8 + h];
        const float* p = QKV + pos * QKVC + h * 192 + d;
        aqi += p[0] * invi;
        ako += p[64] * invo;
    }
    __shared__ float lq[4][64], lk[4][64];
    lq[sub][d] = aqi; lk[sub][d] = ako;
    __syncthreads();
    if (threadIdx.x < 64) {
        pqi[(bh * 16 + sc) * 64 + d] = lq[0][d] + lq[1][d] + lq[2][d] + lq[3][d];
        pko[(bh * 16 + sc) * 64 + d] = lk[0][d] + lk[1][d] + lk[2][d] + lk[3][d];
    }
}

// ---------------- K6: softmax stats over s per (b,h)  (grid: 32 x 256) ----------------
__global__ void softmax_stats(const float* __restrict__ ohat, float* __restrict__ mx, float* __restrict__ sm) {
    int bh = blockIdx.x;
    int b = bh >> 3, h = bh & 7;
    float vals[16];
    float m = -1e30f;
    for (int j = 0; j < 16; ++j) {
        int s = j * 256 + threadIdx.x;
        float v = ohat[((size_t)b * S_ + s) * 8 + h];
        vals[j] = v;
        m = fmaxf(m, v);
    }
    __shared__ float red[256];
    red[threadIdx.x] = m;
    __syncthreads();
    for (int st = 128; st > 0; st >>= 1) {
        if (threadIdx.x < st) red[threadIdx.x] = fmaxf(red[threadIdx.x], red[threadIdx.x + st]);
        __syncthreads();
    }
    m = red[0];
    __syncthreads();
    float ss = 0.f;
    for (int j = 0; j < 16; ++j) ss += expf(vals[j] - m);
    red[threadIdx.x] = ss;
    __syncthreads();
    for (int st = 128; st > 0; st >>= 1) {
        if (threadIdx.x < st) red[threadIdx.x] += red[threadIdx.x + st];
        __syncthreads();
    }
    if (threadIdx.x == 0) { mx[bh] = m; sm[bh] = red[0]; }
}

// ---------------- K7: per-position 8x8 mix -> r (bf16)  (grid: NPOS/4 x 256) ----------------
// r[h,e] = sig(i_hat[h])/i[h] * sum_h' ( sum_d q[h,d]k[h',d] ) * v[h',e]*w[h']
__global__ void finalize_kernel(const float* __restrict__ QKV, const float* __restrict__ iv,
                                const float* __restrict__ ihat, const float* __restrict__ ohat,
                                const float* __restrict__ mxv, const float* __restrict__ smv,
                                u16* __restrict__ rout) {
    __shared__ float qs[4][512];
    __shared__ float ks[4][512];
    __shared__ float Mm[4][64];
    __shared__ float wsc[4][8];
    __shared__ float rowsc[4][8];
    int wv = threadIdx.x >> 6, lane = threadIdx.x & 63;
    int p = blockIdx.x * 4 + wv;
    int b = p >> 12;
    size_t base = (size_t)p * QKVC;
    float vr[8];
    #pragma unroll
    for (int h = 0; h < 8; ++h) {
        qs[wv][h * 64 + lane] = QKV[base + h * 192 + lane];
        ks[wv][h * 64 + lane] = QKV[base + h * 192 + 64 + lane];
        vr[h] = QKV[base + h * 192 + 128 + lane];
    }
    if (lane < 8) {
        int bh = b * 8 + lane;
        wsc[wv][lane] = expf(ohat[(size_t)p * 8 + lane] - mxv[bh]) / smv[bh];
        float sig = 1.f / (1.f + expf(-ihat[(size_t)p * 8 + lane]));
        rowsc[wv][lane] = sig / iv[(size_t)p * 8 + lane];
    }
    __syncthreads();
    {   // M[h,h2], lane-rotated d to keep LDS reads 2-way (free)
        int h = lane >> 3, h2 = lane & 7;
        const float* qrow = &qs[wv][h * 64];
        const float* krow = &ks[wv][h2 * 64];
        float acc = 0.f;
        #pragma unroll 8
        for (int it = 0; it < 64; ++it) {
            int d = (it + lane) & 63;
            acc += qrow[d] * krow[d];
        }
        Mm[wv][lane] = acc * rowsc[wv][h];
    }
    #pragma unroll
    for (int h = 0; h < 8; ++h) vr[h] *= wsc[wv][h];
    __syncthreads();
    #pragma unroll
    for (int h = 0; h < 8; ++h) {
        float acc = 0.f;
        #pragma unroll
        for (int h2 = 0; h2 < 8; ++h2) acc += Mm[wv][h * 8 + h2] * vr[h2];
        rout[(size_t)p * 512 + h * 64 + lane] = f2bf(acc);
    }
}

// ---------------- launch ----------------
extern "C" void kernel_launch(void* const* d_in, const int* in_sizes, int n_in,
                              void* d_out, int out_size, void* d_ws, size_t ws_size,
                              hipStream_t stream) {
    const float* x    = (const float*)d_in[0];
    const float* Wqkv = (const float*)d_in[1];
    const float* bqkv = (const float*)d_in[2];
    const float* Wout = (const float*)d_in[3];
    const float* bout = (const float*)d_in[4];
    float* out = (float*)d_out;
    char* ws = (char*)d_ws;

    // workspace layout (~122 MB total)
    constexpr size_t SZ_XBF  = (size_t)NPOS * E_ * 2;      // 16 MB  (reused for r_bf16)
    constexpr size_t SZ_WQBF = (size_t)QKVC * E_ * 2;      // 1.5 MB
    constexpr size_t SZ_WOBF = (size_t)E_ * E_ * 2;        // 0.5 MB
    constexpr size_t SZ_QKV  = (size_t)NPOS * QKVC * 4;    // 100.7 MB
    constexpr size_t SZ_V8   = (size_t)NPOS * 8 * 4;       // 512 KB each
    constexpr size_t SZ_SUM  = (size_t)32 * 64 * 4;        // 8 KB each
    constexpr size_t SZ_PART = (size_t)32 * 16 * 64 * 4;   // 128 KB each

    size_t off = 0;
    u16*   xbf   = (u16*)(ws + off);   off += SZ_XBF;
    u16*   wqbf  = (u16*)(ws + off);   off += SZ_WQBF;
    u16*   wobf  = (u16*)(ws + off);   off += SZ_WOBF;
    float* qkv   = (float*)(ws + off); off += SZ_QKV;
    float* iv    = (float*)(ws + off); off += SZ_V8;
    float* ov    = (float*)(ws + off); off += SZ_V8;
    float* ihat  = (float*)(ws + off); off += SZ_V8;
    float* ohat  = (float*)(ws + off); off += SZ_V8;
    float* sumq  = (float*)(ws + off); off += SZ_SUM;
    float* sumk  = (float*)(ws + off); off += SZ_SUM;
    float* sumqi = (float*)(ws + off); off += SZ_SUM;
    float* sumko = (float*)(ws + off); off += SZ_SUM;
    float* mx    = (float*)(ws + off); off += 256;
    float* sm    = (float*)(ws + off); off += 256;
    float* pq    = (float*)(ws + off); off += SZ_PART;
    float* pk    = (float*)(ws + off); off += SZ_PART;
    u16*   rbf   = xbf;  // x_bf16 dead after GEMM1; reuse for r (same size)

    // 1) fp32 -> bf16 conversions
    cvt_kernel<<<(NPOS * E_ / 4) / 256, 256, 0, stream>>>((const float4*)x, (u16x4*)xbf, NPOS * E_ / 4);
    cvt_kernel<<<(QKVC * E_ / 4) / 256, 256, 0, stream>>>((const float4*)Wqkv, (u16x4*)wqbf, QKVC * E_ / 4);
    cvt_kernel<<<(E_ * E_ / 4) / 256, 256, 0, stream>>>((const float4*)Wout, (u16x4*)wobf, E_ * E_ / 4);

    // 2) qkv = x @ Wqkv^T + b, sigmoid on q,k channels
    gemm_bt<<<dim3(QKVC / 64, NPOS / 64), 256, 0, stream>>>(xbf, wqbf, bqkv, qkv, NPOS, QKVC, K_, 1);

    // 3) sum_q, sum_k over s
    k2_partial<<<dim3(32, 16), 256, 0, stream>>>(qkv, pq, pk);
    k2_final<<<32, 64, 0, stream>>>(pq, pk, sumq, sumk);

    // 4) i = <q, sum_k>, o = <k, sum_q>
    io_kernel<<<NPOS / 4, 256, 0, stream>>>(qkv, sumk, sumq, iv, ov);

    // 5) sum(q/i), sum(k/o) over s
    k4_partial<<<dim3(32, 16), 256, 0, stream>>>(qkv, iv, ov, pq, pk);
    k2_final<<<32, 64, 0, stream>>>(pq, pk, sumqi, sumko);

    // 6) i_hat = <q, sum(k/o)>, o_hat = <k, sum(q/i)>
    io_kernel<<<NPOS / 4, 256, 0, stream>>>(qkv, sumko, sumqi, ihat, ohat);

    // 7) softmax stats of o_hat over s per (b,h)
    softmax_stats<<<32, 256, 0, stream>>>(ohat, mx, sm);

    // 8) per-position head mix -> r (bf16)
    finalize_kernel<<<NPOS / 4, 256, 0, stream>>>(qkv, iv, ihat, ohat, mx, sm, rbf);

    // 9) out = r @ Wout^T + b_out
    gemm_bt<<<dim3(E_ / 64, NPOS / 64), 256, 0, stream>>>(rbf, wobf, bout, out, NPOS, E_, K_, 0);
}

// Round 2
// 282.756 us; speedup vs baseline: 1.0443x; 1.0443x over previous
//
#include <hip/hip_runtime.h>
#include <cstdint>
#include <cstddef>

// ---------------- problem constants ----------------
#define B_ 4
#define S_ 4096
#define E_ 512
#define H_ 8
#define D_ 64
#define NPOS 16384      // B*S
#define QKVC 1536       // 3*E
#define K_ 512          // contraction dim of both GEMMs
#define NSC 32          // s-chunks for reduction kernels (128 s per block)

typedef unsigned short u16;
typedef u16    u16x8  __attribute__((ext_vector_type(8)));
typedef u16    u16x4  __attribute__((ext_vector_type(4)));
typedef __bf16 bf16x8 __attribute__((ext_vector_type(8)));
typedef float  f32x4  __attribute__((ext_vector_type(4)));

__device__ __forceinline__ u16 f2bf(float f) {
    unsigned u = __builtin_bit_cast(unsigned, f);
    unsigned r = (u + 0x7fffu + ((u >> 16) & 1u)) >> 16;   // RNE, finite inputs
    return (u16)r;
}
__device__ __forceinline__ float bf2f(u16 u) {
    return __builtin_bit_cast(float, (unsigned)u << 16);
}

// async global->LDS, 16B per lane; lds base must be wave-uniform, each lane
// deposits at base + laneid*16  [guide §5, m97/m104]
__device__ __forceinline__ void async16(const void* g, void* lds) {
    __builtin_amdgcn_global_load_lds(
        (const __attribute__((address_space(1))) unsigned int*)g,
        (__attribute__((address_space(3))) unsigned int*)lds, 16, 0, 0);
}

// ---------------- fp32 -> bf16 conversion (vectorized x4) ----------------
__global__ void cvt_kernel(const float4* __restrict__ in, u16x4* __restrict__ out, int n4) {
    int i = blockIdx.x * 256 + threadIdx.x;
    if (i < n4) {
        float4 v = in[i];
        u16x4 o;
        o[0] = f2bf(v.x); o[1] = f2bf(v.y); o[2] = f2bf(v.z); o[3] = f2bf(v.w);
        out[i] = o;
    }
}

// ---------------- bf16 MFMA GEMM, m97 structure ----------------
// C[M,N] = A[M,K] @ B[N,K]^T + bias.  128x128 tile, 4 waves in 2x2 (each 64x64
// = 4x4 MFMA 16x16x32), BK=32, LDS unpadded (global_load_lds constraint).
// ACT==1: bf16 out, sigmoid on cols with (n%192)<128.  ACT==0: fp32 out.
template <int ACT>
__global__ __launch_bounds__(256) void gemm128(
        const u16* __restrict__ A, const u16* __restrict__ Bw,
        const float* __restrict__ bias, void* __restrict__ Cout,
        int M, int N, int K) {
    __shared__ u16 As[128 * 32];   // 8 KB, row-major, 32 elems (64B) per row
    __shared__ u16 Bs[128 * 32];
    const int tid  = threadIdx.x;
    const int wave = tid >> 6, lane = tid & 63;
    const int m0 = blockIdx.y * 128, n0 = blockIdx.x * 128;
    const int wm = (wave & 1) * 64, wn = (wave >> 1) * 64;

    // staging: wave w, call c covers rows c*64 + w*16 .. +15; lane L -> row
    // base + (L>>2), elem col (L&3)*8.  LDS elem offset = c*2048 + w*512 + L*8.
    const int srow = wave * 16 + (lane >> 2);
    const int scol = (lane & 3) * 8;
    const u16* Ap = A  + (size_t)(m0 + srow) * K + scol;
    const u16* Bp = Bw + (size_t)(n0 + srow) * K + scol;
    u16* AsW = &As[wave * 512];
    u16* BsW = &Bs[wave * 512];
    const size_t rstep = (size_t)64 * K;

    f32x4 acc[4][4] = {};
    const int fr = lane & 15, fk = (lane >> 4) * 8;

    for (int k0 = 0; k0 < K; k0 += 32) {
        async16(Ap + k0,         AsW);
        async16(Ap + k0 + rstep, AsW + 2048);
        async16(Bp + k0,         BsW);
        async16(Bp + k0 + rstep, BsW + 2048);
        __syncthreads();
        bf16x8 a[4], b[4];
        #pragma unroll
        for (int i = 0; i < 4; ++i)
            a[i] = *(const bf16x8*)&As[(wm + i * 16 + fr) * 32 + fk];
        #pragma unroll
        for (int j = 0; j < 4; ++j)
            b[j] = *(const bf16x8*)&Bs[(wn + j * 16 + fr) * 32 + fk];
        #pragma unroll
        for (int i = 0; i < 4; ++i)
            #pragma unroll
            for (int j = 0; j < 4; ++j)
                acc[i][j] = __builtin_amdgcn_mfma_f32_16x16x32_bf16(a[i], b[j], acc[i][j], 0, 0, 0);
        __syncthreads();
    }

    // epilogue: C/D layout col = lane&15, row = (lane>>4)*4 + reg  [m89/m91]
    const int cn = lane & 15, rb = (lane >> 4) * 4;
    #pragma unroll
    for (int i = 0; i < 4; ++i) {
        int mbase = m0 + wm + i * 16 + rb;
        #pragma unroll
        for (int j = 0; j < 4; ++j) {
            int nn = n0 + wn + j * 16 + cn;
            float bv = bias[nn];
            f32x4 av = acc[i][j];
            if (ACT == 1) {
                bool sg = (nn % 192) < 128;
                u16* C = (u16*)Cout;
                #pragma unroll
                for (int r = 0; r < 4; ++r) {
                    float v = av[r] + bv;
                    if (sg) v = 1.f / (1.f + __expf(-v));
                    C[(size_t)(mbase + r) * N + nn] = f2bf(v);
                }
            } else {
                float* C = (float*)Cout;
                #pragma unroll
                for (int r = 0; r < 4; ++r)
                    C[(size_t)(mbase + r) * N + nn] = av[r] + bv;
            }
        }
    }
}

// ---------------- A: partial sums over s of q,k  (grid: (32 bh, NSC) x 256) ----------------
__global__ void sum_qk(const u16* __restrict__ QKV, float* __restrict__ pq, float* __restrict__ pk) {
    int bh = blockIdx.x, sc = blockIdx.y;
    int b = bh >> 3, h = bh & 7;
    int d = threadIdx.x & 63, sub = threadIdx.x >> 6;
    int s0 = sc * 128 + sub * 32;
    float aq = 0.f, ak = 0.f;
    size_t base = (size_t)b * S_ * QKVC + h * 192 + d;
    for (int s = s0; s < s0 + 32; ++s) {
        const u16* p = QKV + base + (size_t)s * QKVC;
        aq += bf2f(p[0]);
        ak += bf2f(p[64]);
    }
    __shared__ float lq[4][64], lk[4][64];
    lq[sub][d] = aq; lk[sub][d] = ak;
    __syncthreads();
    if (threadIdx.x < 64) {
        pq[(bh * NSC + sc) * 64 + d] = lq[0][d] + lq[1][d] + lq[2][d] + lq[3][d];
        pk[(bh * NSC + sc) * 64 + d] = lk[0][d] + lk[1][d] + lk[2][d] + lk[3][d];
    }
}

// ---------------- fold NSC partials  (grid: 32 x 64) ----------------
__global__ void k2_final(const float* __restrict__ pa, const float* __restrict__ pb,
                         float* __restrict__ oa, float* __restrict__ ob) {
    int bh = blockIdx.x, d = threadIdx.x;
    float aa = 0.f, ab = 0.f;
    for (int c = 0; c < NSC; ++c) {
        aa += pa[(bh * NSC + c) * 64 + d];
        ab += pb[(bh * NSC + c) * 64 + d];
    }
    oa[bh * 64 + d] = aa;
    ob[bh * 64 + d] = ab;
}

// ---------------- B: fused i/o dots + partial sums of q/i, k/o ----------------
// grid: (32 bh, NSC) x 256.  i,o computed in-register and consumed immediately;
// only iv is stored (o is dead after this kernel).
__global__ void fused_io_k4(const u16* __restrict__ QKV,
                            const float* __restrict__ sumk, const float* __restrict__ sumq,
                            float* __restrict__ iv,
                            float* __restrict__ pqi, float* __restrict__ pko) {
    int bh = blockIdx.x, sc = blockIdx.y;
    int b = bh >> 3, h = bh & 7;
    int lane = threadIdx.x & 63, sub = threadIdx.x >> 6;
    float vA = sumk[bh * 64 + lane];   // i = <q, sum_k>
    float vB = sumq[bh * 64 + lane];   // o = <k, sum_q>
    int s0 = sc * 128 + sub * 32;
    float aqi = 0.f, ako = 0.f;
    for (int s = s0; s < s0 + 32; ++s) {
        size_t pos = (size_t)b * S_ + s;
        const u16* p = QKV + pos * QKVC + h * 192 + lane;
        float q = bf2f(p[0]), k = bf2f(p[64]);
        float vi = q * vA, vo = k * vB;
        #pragma unroll
        for (int off = 32; off > 0; off >>= 1) {
            vi += __shfl_xor(vi, off);
            vo += __shfl_xor(vo, off);
        }
        if (lane == 0) iv[pos * 8 + h] = vi;
        aqi += q / vi;
        ako += k / vo;
    }
    __shared__ float lq[4][64], lk[4][64];
    lq[sub][lane] = aqi; lk[sub][lane] = ako;
    __syncthreads();
    if (threadIdx.x < 64) {
        pqi[(bh * NSC + sc) * 64 + lane] = lq[0][lane] + lq[1][lane] + lq[2][lane] + lq[3][lane];
        pko[(bh * NSC + sc) * 64 + lane] = lk[0][lane] + lk[1][lane] + lk[2][lane] + lk[3][lane];
    }
}

// ---------------- C: i_hat = <q, sum(k/o)>, o_hat = <k, sum(q/i)>  (grid NPOS/4 x 256) ----------------
__global__ void io2_kernel(const u16* __restrict__ QKV,
                           const float* __restrict__ sumko, const float* __restrict__ sumqi,
                           float* __restrict__ ihat, float* __restrict__ ohat) {
    int wv = threadIdx.x >> 6, lane = threadIdx.x & 63;
    int p = blockIdx.x * 4 + wv;
    int b = p >> 12;
    size_t base = (size_t)p * QKVC;
    for (int h = 0; h < 8; ++h) {
        float q = bf2f(QKV[base + h * 192 + lane]);
        float k = bf2f(QKV[base + h * 192 + 64 + lane]);
        float vi = q * sumko[(b * 8 + h) * 64 + lane];
        float vo = k * sumqi[(b * 8 + h) * 64 + lane];
        #pragma unroll
        for (int off = 32; off > 0; off >>= 1) {
            vi += __shfl_xor(vi, off);
            vo += __shfl_xor(vo, off);
        }
        if (lane == 0) {
            ihat[(size_t)p * 8 + h] = vi;
            ohat[(size_t)p * 8 + h] = vo;
        }
    }
}

// ---------------- softmax stats over s per (b,h)  (grid: 32 x 256) ----------------
__global__ void softmax_stats(const float* __restrict__ ohat, float* __restrict__ mx, float* __restrict__ sm) {
    int bh = blockIdx.x;
    int b = bh >> 3, h = bh & 7;
    float vals[16];
    float m = -1e30f;
    for (int j = 0; j < 16; ++j) {
        int s = j * 256 + threadIdx.x;
        float v = ohat[((size_t)b * S_ + s) * 8 + h];
        vals[j] = v;
        m = fmaxf(m, v);
    }
    __shared__ float red[256];
    red[threadIdx.x] = m;
    __syncthreads();
    for (int st = 128; st > 0; st >>= 1) {
        if (threadIdx.x < st) red[threadIdx.x] = fmaxf(red[threadIdx.x], red[threadIdx.x + st]);
        __syncthreads();
    }
    m = red[0];
    __syncthreads();
    float ss = 0.f;
    for (int j = 0; j < 16; ++j) ss += __expf(vals[j] - m);
    red[threadIdx.x] = ss;
    __syncthreads();
    for (int st = 128; st > 0; st >>= 1) {
        if (threadIdx.x < st) red[threadIdx.x] += red[threadIdx.x + st];
        __syncthreads();
    }
    if (threadIdx.x == 0) { mx[bh] = m; sm[bh] = red[0]; }
}

// ---------------- finalize: per-position 8x8 head mix -> r (bf16)  (grid NPOS/4 x 256) ----------------
// r[h,e] = sig(i_hat[h])/i[h] * sum_h' ( sum_d q[h,d]k[h',d] ) * v[h',e]*w[h']
__global__ __launch_bounds__(256) void finalize_kernel(
        const u16* __restrict__ QKV, const float* __restrict__ iv,
        const float* __restrict__ ihat, const float* __restrict__ ohat,
        const float* __restrict__ mxv, const float* __restrict__ smv,
        u16* __restrict__ rout) {
    __shared__ float qs[4][512];
    __shared__ float ks[4][512];
    __shared__ float vs[4][512];
    __shared__ float Mm[4][64];
    __shared__ float wsc[4][8];
    __shared__ float rowsc[4][8];
    int wv = threadIdx.x >> 6, lane = threadIdx.x & 63;
    int p = blockIdx.x * 4 + wv;
    int b = p >> 12;
    const u16* row = QKV + (size_t)p * QKVC;

    // coalesced row load: 3 x 16B per lane; each 8-elem chunk lands in one
    // (head, q/k/v) segment since segments are 64-aligned.
    #pragma unroll
    for (int part = 0; part < 3; ++part) {
        int e = part * 512 + lane * 8;
        int h = e / 192, r = e - h * 192;
        int t = r >> 6, d0 = r & 63;
        u16x8 c = *(const u16x8*)(row + e);
        float* dst = (t == 0) ? &qs[wv][h * 64 + d0]
                   : (t == 1) ? &ks[wv][h * 64 + d0]
                              : &vs[wv][h * 64 + d0];
        #pragma unroll
        for (int j = 0; j < 8; ++j) dst[j] = bf2f(c[j]);
    }
    if (lane < 8) {
        int bh = b * 8 + lane;
        wsc[wv][lane] = __expf(ohat[(size_t)p * 8 + lane] - mxv[bh]) / smv[bh];
        float sig = 1.f / (1.f + __expf(-ihat[(size_t)p * 8 + lane]));
        rowsc[wv][lane] = sig / iv[(size_t)p * 8 + lane];
    }
    __syncthreads();
    {   // M[h,h2], lane-rotated d: 2-way bank aliasing only (free)
        int h = lane >> 3, h2 = lane & 7;
        const float* qrow = &qs[wv][h * 64];
        const float* krow = &ks[wv][h2 * 64];
        float acc = 0.f;
        #pragma unroll 8
        for (int it = 0; it < 64; ++it) {
            int d = (it + lane) & 63;
            acc += qrow[d] * krow[d];
        }
        Mm[wv][lane] = acc * rowsc[wv][h];
    }
    __syncthreads();
    float vr[8];
    #pragma unroll
    for (int h2 = 0; h2 < 8; ++h2) vr[h2] = vs[wv][h2 * 64 + lane] * wsc[wv][h2];
    #pragma unroll
    for (int h = 0; h < 8; ++h) {
        float acc = 0.f;
        #pragma unroll
        for (int h2 = 0; h2 < 8; ++h2) acc += Mm[wv][h * 8 + h2] * vr[h2];
        rout[(size_t)p * 512 + h * 64 + lane] = f2bf(acc);
    }
}

// ---------------- launch ----------------
extern "C" void kernel_launch(void* const* d_in, const int* in_sizes, int n_in,
                              void* d_out, int out_size, void* d_ws, size_t ws_size,
                              hipStream_t stream) {
    const float* x    = (const float*)d_in[0];
    const float* Wqkv = (const float*)d_in[1];
    const float* bqkv = (const float*)d_in[2];
    const float* Wout = (const float*)d_in[3];
    const float* bout = (const float*)d_in[4];
    float* out = (float*)d_out;
    char* ws = (char*)d_ws;

    // workspace layout (~72 MB)
    constexpr size_t SZ_XBF  = (size_t)NPOS * E_ * 2;        // 16 MB (reused for r_bf16)
    constexpr size_t SZ_WQBF = (size_t)QKVC * E_ * 2;        // 1.5 MB
    constexpr size_t SZ_WOBF = (size_t)E_ * E_ * 2;          // 0.5 MB
    constexpr size_t SZ_QKV  = (size_t)NPOS * QKVC * 2;      // 50.3 MB (bf16)
    constexpr size_t SZ_V8   = (size_t)NPOS * 8 * 4;         // 512 KB each
    constexpr size_t SZ_SUM  = (size_t)32 * 64 * 4;          // 8 KB each
    constexpr size_t SZ_PART = (size_t)32 * NSC * 64 * 4;    // 256 KB each

    size_t off = 0;
    u16*   xbf   = (u16*)(ws + off);   off += SZ_XBF;
    u16*   wqbf  = (u16*)(ws + off);   off += SZ_WQBF;
    u16*   wobf  = (u16*)(ws + off);   off += SZ_WOBF;
    u16*   qkv   = (u16*)(ws + off);   off += SZ_QKV;
    float* iv    = (float*)(ws + off); off += SZ_V8;
    float* ihat  = (float*)(ws + off); off += SZ_V8;
    float* ohat  = (float*)(ws + off); off += SZ_V8;
    float* sumq  = (float*)(ws + off); off += SZ_SUM;
    float* sumk  = (float*)(ws + off); off += SZ_SUM;
    float* sumqi = (float*)(ws + off); off += SZ_SUM;
    float* sumko = (float*)(ws + off); off += SZ_SUM;
    float* mx    = (float*)(ws + off); off += 256;
    float* sm    = (float*)(ws + off); off += 256;
    float* pq    = (float*)(ws + off); off += SZ_PART;
    float* pk    = (float*)(ws + off); off += SZ_PART;
    u16*   rbf   = xbf;  // x_bf16 dead after GEMM1; reuse for r

    // 1) fp32 -> bf16 conversions
    cvt_kernel<<<(NPOS * E_ / 4) / 256, 256, 0, stream>>>((const float4*)x, (u16x4*)xbf, NPOS * E_ / 4);
    cvt_kernel<<<(QKVC * E_ / 4) / 256, 256, 0, stream>>>((const float4*)Wqkv, (u16x4*)wqbf, QKVC * E_ / 4);
    cvt_kernel<<<(E_ * E_ / 4) / 256, 256, 0, stream>>>((const float4*)Wout, (u16x4*)wobf, E_ * E_ / 4);

    // 2) qkv = sigmoid_qk(x @ Wqkv^T + b) in bf16
    gemm128<1><<<dim3(QKVC / 128, NPOS / 128), 256, 0, stream>>>(xbf, wqbf, bqkv, qkv, NPOS, QKVC, K_);

    // 3) sum_q, sum_k over s
    sum_qk<<<dim3(32, NSC), 256, 0, stream>>>(qkv, pq, pk);
    k2_final<<<32, 64, 0, stream>>>(pq, pk, sumq, sumk);

    // 4+5) i,o dots fused with partial sums of q/i, k/o
    fused_io_k4<<<dim3(32, NSC), 256, 0, stream>>>(qkv, sumk, sumq, iv, pq, pk);
    k2_final<<<32, 64, 0, stream>>>(pq, pk, sumqi, sumko);

    // 6) i_hat, o_hat
    io2_kernel<<<NPOS / 4, 256, 0, stream>>>(qkv, sumko, sumqi, ihat, ohat);

    // 7) softmax stats of o_hat
    softmax_stats<<<32, 256, 0, stream>>>(ohat, mx, sm);

    // 8) per-position head mix -> r (bf16)
    finalize_kernel<<<NPOS / 4, 256, 0, stream>>>(qkv, iv, ihat, ohat, mx, sm, rbf);

    // 9) out = r @ Wout^T + b_out (fp32)
    gemm128<0><<<dim3(E_ / 128, NPOS / 128), 256, 0, stream>>>(rbf, wobf, bout, out, NPOS, E_, K_);
}

// Round 3
// 199.281 us; speedup vs baseline: 1.4818x; 1.4189x over previous
//
#include <hip/hip_runtime.h>
#include <cstdint>
#include <cstddef>

// ---------------- problem constants ----------------
#define B_ 4
#define S_ 4096
#define E_ 512
#define NPOS 16384      // B*S
#define QKVC 1536       // 3*E
#define K_ 512          // contraction dim of both GEMMs

typedef unsigned short u16;
typedef u16    u16x8  __attribute__((ext_vector_type(8)));
typedef u16    u16x4  __attribute__((ext_vector_type(4)));
typedef __bf16 bf16x8 __attribute__((ext_vector_type(8)));
typedef float  f32x4  __attribute__((ext_vector_type(4)));

__device__ __forceinline__ u16 f2bf(float f) {
    unsigned u = __builtin_bit_cast(unsigned, f);
    unsigned r = (u + 0x7fffu + ((u >> 16) & 1u)) >> 16;   // RNE, finite inputs
    return (u16)r;
}
__device__ __forceinline__ float bf2f(u16 u) {
    return __builtin_bit_cast(float, (unsigned)u << 16);
}
__device__ __forceinline__ float rcpf(float x) { return __builtin_amdgcn_rcpf(x); }

// async global->LDS, 16B per lane; lds base wave-uniform, lane deposits at
// base + laneid*16  [guide §5, m97/m104]
__device__ __forceinline__ void async16(const void* g, void* lds) {
    __builtin_amdgcn_global_load_lds(
        (const __attribute__((address_space(1))) unsigned int*)g,
        (__attribute__((address_space(3))) unsigned int*)lds, 16, 0, 0);
}

// ---------------- fp32 -> bf16 conversion ----------------
__global__ void cvt_kernel(const float4* __restrict__ in, u16x4* __restrict__ out, int n4) {
    int i = blockIdx.x * 256 + threadIdx.x;
    if (i < n4) {
        float4 v = in[i];
        u16x4 o;
        o[0] = f2bf(v.x); o[1] = f2bf(v.y); o[2] = f2bf(v.z); o[3] = f2bf(v.w);
        out[i] = o;
    }
}

// ---------------- GEMM1: qkv = sigmoid_qk(x @ Wqkv^T + b), de-interleaved bf16 out ----------------
// 128x128 tile, m97 structure.  Output channel nn -> col64 = nn/64,
// type = col64 % 3 (0=q sig,1=k sig,2=v), head-block = col64/3.
__global__ __launch_bounds__(256) void gemm_qkv(
        const u16* __restrict__ A, const u16* __restrict__ Bw,
        const float* __restrict__ bias,
        u16* __restrict__ Qb, u16* __restrict__ Kb, u16* __restrict__ Vb,
        int K) {
    __shared__ u16 As[128 * 32];
    __shared__ u16 Bs[128 * 32];
    const int tid  = threadIdx.x;
    const int wave = tid >> 6, lane = tid & 63;
    const int m0 = blockIdx.y * 128, n0 = blockIdx.x * 128;
    const int wm = (wave & 1) * 64, wn = (wave >> 1) * 64;

    const int srow = wave * 16 + (lane >> 2);
    const int scol = (lane & 3) * 8;
    const u16* Ap = A  + (size_t)(m0 + srow) * K + scol;
    const u16* Bp = Bw + (size_t)(n0 + srow) * K + scol;
    u16* AsW = &As[wave * 512];
    u16* BsW = &Bs[wave * 512];
    const size_t rstep = (size_t)64 * K;

    f32x4 acc[4][4] = {};
    const int fr = lane & 15, fk = (lane >> 4) * 8;

    for (int k0 = 0; k0 < K; k0 += 32) {
        async16(Ap + k0,         AsW);
        async16(Ap + k0 + rstep, AsW + 2048);
        async16(Bp + k0,         BsW);
        async16(Bp + k0 + rstep, BsW + 2048);
        __syncthreads();
        bf16x8 a[4], b[4];
        #pragma unroll
        for (int i = 0; i < 4; ++i)
            a[i] = *(const bf16x8*)&As[(wm + i * 16 + fr) * 32 + fk];
        #pragma unroll
        for (int j = 0; j < 4; ++j)
            b[j] = *(const bf16x8*)&Bs[(wn + j * 16 + fr) * 32 + fk];
        #pragma unroll
        for (int i = 0; i < 4; ++i)
            #pragma unroll
            for (int j = 0; j < 4; ++j)
                acc[i][j] = __builtin_amdgcn_mfma_f32_16x16x32_bf16(a[i], b[j], acc[i][j], 0, 0, 0);
        __syncthreads();
    }

    // epilogue: C/D col = lane&15, row = (lane>>4)*4 + reg   [m89/m91]
    const int cn = lane & 15, rb = (lane >> 4) * 4;
    const int cg   = (n0 + wn) >> 6;      // wave-uniform 64-col group
    const int type = cg % 3;
    const int hb   = cg / 3;
    u16* dst = (type == 0) ? Qb : (type == 1) ? Kb : Vb;
    const bool sg = (type < 2);
    #pragma unroll
    for (int i = 0; i < 4; ++i) {
        int mbase = m0 + wm + i * 16 + rb;
        #pragma unroll
        for (int j = 0; j < 4; ++j) {
            int ccol = j * 16 + cn;                     // 0..63 within group
            float bv = bias[n0 + wn + ccol];
            int outcol = hb * 64 + ccol;
            f32x4 av = acc[i][j];
            #pragma unroll
            for (int r = 0; r < 4; ++r) {
                float v = av[r] + bv;
                if (sg) v = 1.f / (1.f + __expf(-v));
                dst[(size_t)(mbase + r) * 512 + outcol] = f2bf(v);
            }
        }
    }
}

// ---------------- GEMM2: out = r @ Wout^T + b (fp32 out) ----------------
__global__ __launch_bounds__(256) void gemm_out(
        const u16* __restrict__ A, const u16* __restrict__ Bw,
        const float* __restrict__ bias, float* __restrict__ C,
        int N, int K) {
    __shared__ u16 As[128 * 32];
    __shared__ u16 Bs[128 * 32];
    const int tid  = threadIdx.x;
    const int wave = tid >> 6, lane = tid & 63;
    const int m0 = blockIdx.y * 128, n0 = blockIdx.x * 128;
    const int wm = (wave & 1) * 64, wn = (wave >> 1) * 64;
    const int srow = wave * 16 + (lane >> 2);
    const int scol = (lane & 3) * 8;
    const u16* Ap = A  + (size_t)(m0 + srow) * K + scol;
    const u16* Bp = Bw + (size_t)(n0 + srow) * K + scol;
    u16* AsW = &As[wave * 512];
    u16* BsW = &Bs[wave * 512];
    const size_t rstep = (size_t)64 * K;
    f32x4 acc[4][4] = {};
    const int fr = lane & 15, fk = (lane >> 4) * 8;
    for (int k0 = 0; k0 < K; k0 += 32) {
        async16(Ap + k0,         AsW);
        async16(Ap + k0 + rstep, AsW + 2048);
        async16(Bp + k0,         BsW);
        async16(Bp + k0 + rstep, BsW + 2048);
        __syncthreads();
        bf16x8 a[4], b[4];
        #pragma unroll
        for (int i = 0; i < 4; ++i)
            a[i] = *(const bf16x8*)&As[(wm + i * 16 + fr) * 32 + fk];
        #pragma unroll
        for (int j = 0; j < 4; ++j)
            b[j] = *(const bf16x8*)&Bs[(wn + j * 16 + fr) * 32 + fk];
        #pragma unroll
        for (int i = 0; i < 4; ++i)
            #pragma unroll
            for (int j = 0; j < 4; ++j)
                acc[i][j] = __builtin_amdgcn_mfma_f32_16x16x32_bf16(a[i], b[j], acc[i][j], 0, 0, 0);
        __syncthreads();
    }
    const int cn = lane & 15, rb = (lane >> 4) * 4;
    #pragma unroll
    for (int i = 0; i < 4; ++i) {
        int mbase = m0 + wm + i * 16 + rb;
        #pragma unroll
        for (int j = 0; j < 4; ++j) {
            int nn = n0 + wn + j * 16 + cn;
            float bv = bias[nn];
            f32x4 av = acc[i][j];
            #pragma unroll
            for (int r = 0; r < 4; ++r)
                C[(size_t)(mbase + r) * N + nn] = av[r] + bv;
        }
    }
}

// ---------------- sum over s of q and k  (grid (4, 128) x 256) ----------------
__global__ __launch_bounds__(256) void sum_qk(const u16* __restrict__ Qg, const u16* __restrict__ Kg,
                                              float* __restrict__ sumq, float* __restrict__ sumk) {
    int b = blockIdx.x, sc = blockIdx.y;
    int w = threadIdx.x >> 6, lane = threadIdx.x & 63;
    float aq[8] = {}, ak[8] = {};
    int p0 = b * S_ + sc * 32 + w * 8;
    for (int it = 0; it < 8; ++it) {
        size_t off = (size_t)(p0 + it) * 512 + lane * 8;
        u16x8 q8 = *(const u16x8*)(Qg + off);
        u16x8 k8 = *(const u16x8*)(Kg + off);
        #pragma unroll
        for (int j = 0; j < 8; ++j) { aq[j] += bf2f(q8[j]); ak[j] += bf2f(k8[j]); }
    }
    __shared__ float red[4][1024];
    #pragma unroll
    for (int j = 0; j < 8; ++j) {
        red[w][lane * 8 + j]       = aq[j];
        red[w][512 + lane * 8 + j] = ak[j];
    }
    __syncthreads();
    int t = threadIdx.x;
    #pragma unroll
    for (int rr = 0; rr < 4; ++rr) {
        int slot = rr * 256 + t;
        float s = red[0][slot] + red[1][slot] + red[2][slot] + red[3][slot];
        float* dst = (slot < 512) ? &sumq[b * 512 + slot] : &sumk[b * 512 + (slot - 512)];
        atomicAdd(dst, s);
    }
}

// ---------------- fused: i,o dots + partial sums of q/i, k/o  (grid (4,128) x 256) ----------------
__global__ __launch_bounds__(256) void fused_io(const u16* __restrict__ Qg, const u16* __restrict__ Kg,
                                                const float* __restrict__ sumq, const float* __restrict__ sumk,
                                                float* __restrict__ iv,
                                                float* __restrict__ sumqi, float* __restrict__ sumko) {
    int b = blockIdx.x, sc = blockIdx.y;
    int w = threadIdx.x >> 6, lane = threadIdx.x & 63;
    float skL[8], sqL[8];
    #pragma unroll
    for (int j = 0; j < 8; ++j) {
        skL[j] = sumk[b * 512 + lane * 8 + j];
        sqL[j] = sumq[b * 512 + lane * 8 + j];
    }
    float aqi[8] = {}, ako[8] = {};
    int p0 = b * S_ + sc * 32 + w * 8;
    for (int it = 0; it < 8; ++it) {
        int p = p0 + it;
        size_t off = (size_t)p * 512 + lane * 8;
        u16x8 q8 = *(const u16x8*)(Qg + off);
        u16x8 k8 = *(const u16x8*)(Kg + off);
        float qf[8], kf[8];
        #pragma unroll
        for (int j = 0; j < 8; ++j) { qf[j] = bf2f(q8[j]); kf[j] = bf2f(k8[j]); }
        float di = 0.f, dox = 0.f;
        #pragma unroll
        for (int j = 0; j < 8; ++j) { di += qf[j] * skL[j]; dox += kf[j] * sqL[j]; }
        di  += __shfl_xor(di, 1);  di  += __shfl_xor(di, 2);  di  += __shfl_xor(di, 4);
        dox += __shfl_xor(dox, 1); dox += __shfl_xor(dox, 2); dox += __shfl_xor(dox, 4);
        if ((lane & 7) == 0) iv[(size_t)p * 8 + (lane >> 3)] = di;
        float ri = rcpf(di), ro = rcpf(dox);
        #pragma unroll
        for (int j = 0; j < 8; ++j) { aqi[j] += qf[j] * ri; ako[j] += kf[j] * ro; }
    }
    __shared__ float red[4][1024];
    #pragma unroll
    for (int j = 0; j < 8; ++j) {
        red[w][lane * 8 + j]       = aqi[j];
        red[w][512 + lane * 8 + j] = ako[j];
    }
    __syncthreads();
    int t = threadIdx.x;
    #pragma unroll
    for (int rr = 0; rr < 4; ++rr) {
        int slot = rr * 256 + t;
        float s = red[0][slot] + red[1][slot] + red[2][slot] + red[3][slot];
        float* dst = (slot < 512) ? &sumqi[b * 512 + slot] : &sumko[b * 512 + (slot - 512)];
        atomicAdd(dst, s);
    }
}

// ---------------- io2: i_hat,o_hat -> rowsc, wexp, sm partials  (grid (4,128) x 256) ----------------
__global__ __launch_bounds__(256) void io2_kernel(const u16* __restrict__ Qg, const u16* __restrict__ Kg,
                                                  const float* __restrict__ sumqi, const float* __restrict__ sumko,
                                                  const float* __restrict__ iv,
                                                  float* __restrict__ rowsc, float* __restrict__ wexp,
                                                  float* __restrict__ sm) {
    int b = blockIdx.x, sc = blockIdx.y;
    int w = threadIdx.x >> 6, lane = threadIdx.x & 63;
    float skoL[8], sqiL[8];
    #pragma unroll
    for (int j = 0; j < 8; ++j) {
        skoL[j] = sumko[b * 512 + lane * 8 + j];
        sqiL[j] = sumqi[b * 512 + lane * 8 + j];
    }
    float smacc = 0.f;
    int p0 = b * S_ + sc * 32 + w * 8;
    for (int it = 0; it < 8; ++it) {
        int p = p0 + it;
        size_t off = (size_t)p * 512 + lane * 8;
        u16x8 q8 = *(const u16x8*)(Qg + off);
        u16x8 k8 = *(const u16x8*)(Kg + off);
        float dih = 0.f, doh = 0.f;
        #pragma unroll
        for (int j = 0; j < 8; ++j) {
            dih += bf2f(q8[j]) * skoL[j];
            doh += bf2f(k8[j]) * sqiL[j];
        }
        dih += __shfl_xor(dih, 1); dih += __shfl_xor(dih, 2); dih += __shfl_xor(dih, 4);
        doh += __shfl_xor(doh, 1); doh += __shfl_xor(doh, 2); doh += __shfl_xor(doh, 4);
        if ((lane & 7) == 0) {
            int h = lane >> 3;
            float sig = 1.f / (1.f + __expf(-dih));
            rowsc[(size_t)p * 8 + h] = sig * rcpf(iv[(size_t)p * 8 + h]);
            float we = __expf(fminf(doh, 80.f));   // softmax w/o max-sub: o_hat ~ O(1)
            wexp[(size_t)p * 8 + h] = we;
            smacc += we;
        }
    }
    __shared__ float sr[4][8];
    if ((lane & 7) == 0) sr[w][lane >> 3] = smacc;
    __syncthreads();
    if (threadIdx.x < 8)
        atomicAdd(&sm[b * 8 + threadIdx.x],
                  sr[0][threadIdx.x] + sr[1][threadIdx.x] + sr[2][threadIdx.x] + sr[3][threadIdx.x]);
}

// ---------------- finalize: MFMA QK^T (2 pos/wave) + PV mix -> r bf16  (grid NPOS/8 x 256) ----------------
__global__ __launch_bounds__(256) void finalize_kernel(
        const u16* __restrict__ Qg, const u16* __restrict__ Kg, const u16* __restrict__ Vg,
        const float* __restrict__ rowsc, const float* __restrict__ wexp, const float* __restrict__ sm,
        u16* __restrict__ Rg) {
    __shared__ float Ml[4][2][8][9];
    __shared__ float vw[4][2][8][68];
    int w = threadIdx.x >> 6, lane = threadIdx.x & 63;
    int p0 = (blockIdx.x * 4 + w) * 2;
    int b = p0 >> 12;

    // QK^T via MFMA: A rows m = (p_l, h) from Q, B rows n = (p_l, h2) from K.
    // A[m=lane&15][k=(lane>>4)*8+j]  [guide §3/§5]
    {
        int pl = (lane >> 3) & 1, hh = lane & 7, quad = lane >> 4;
        const u16* qa = Qg + (size_t)(p0 + pl) * 512 + hh * 64 + quad * 8;
        const u16* ka = Kg + (size_t)(p0 + pl) * 512 + hh * 64 + quad * 8;
        bf16x8 a0 = __builtin_bit_cast(bf16x8, *(const u16x8*)qa);
        bf16x8 a1 = __builtin_bit_cast(bf16x8, *(const u16x8*)(qa + 32));
        bf16x8 b0 = __builtin_bit_cast(bf16x8, *(const u16x8*)ka);
        bf16x8 b1 = __builtin_bit_cast(bf16x8, *(const u16x8*)(ka + 32));
        f32x4 accm = {0.f, 0.f, 0.f, 0.f};
        accm = __builtin_amdgcn_mfma_f32_16x16x32_bf16(a0, b0, accm, 0, 0, 0);
        accm = __builtin_amdgcn_mfma_f32_16x16x32_bf16(a1, b1, accm, 0, 0, 0);
        // C: row=(lane>>4)*4+r, col=lane&15.  Keep diagonal p-quadrants.
        if (((lane >> 5) & 1) == ((lane >> 3) & 1)) {
            int plm = lane >> 5, hr = ((lane >> 4) & 1) * 4, h2 = lane & 7;
            #pragma unroll
            for (int r = 0; r < 4; ++r) Ml[w][plm][hr + r][h2] = accm[r];
        }
    }
    // vw = v * softmax-weight, fp32 in LDS
    {
        int hv = lane >> 3, e0 = (lane & 7) * 8;
        float invsm = rcpf(sm[b * 8 + hv]);
        #pragma unroll
        for (int pl = 0; pl < 2; ++pl) {
            u16x8 v8 = *(const u16x8*)(Vg + (size_t)(p0 + pl) * 512 + lane * 8);
            float wgt = wexp[(size_t)(p0 + pl) * 8 + hv] * invsm;
            f32x4 x0, x1;
            #pragma unroll
            for (int j = 0; j < 4; ++j) { x0[j] = bf2f(v8[j]) * wgt; x1[j] = bf2f(v8[4 + j]) * wgt; }
            *(f32x4*)&vw[w][pl][hv][e0]     = x0;
            *(f32x4*)&vw[w][pl][hv][e0 + 4] = x1;
        }
    }
    __syncthreads();   // order intra-wave cross-lane LDS deps safely
    // PV: lane covers (p_l = lane>>5, h = (lane&31)>>2, 16-elem e-chunk)
    {
        int pl = lane >> 5, idx = lane & 31, h = idx >> 2, eq = (idx & 3) * 16;
        float out[16] = {};
        #pragma unroll
        for (int h2 = 0; h2 < 8; ++h2) {
            float m = Ml[w][pl][h][h2];
            #pragma unroll
            for (int c = 0; c < 4; ++c) {
                f32x4 vv = *(const f32x4*)&vw[w][pl][h2][eq + c * 4];
                #pragma unroll
                for (int j = 0; j < 4; ++j) out[c * 4 + j] += m * vv[j];
            }
        }
        float rs = rowsc[(size_t)(p0 + pl) * 8 + h];
        u16x8 o0, o1;
        #pragma unroll
        for (int j = 0; j < 8; ++j) { o0[j] = f2bf(out[j] * rs); o1[j] = f2bf(out[8 + j] * rs); }
        u16* dst = Rg + (size_t)(p0 + pl) * 512 + h * 64 + eq;
        *(u16x8*)dst       = o0;
        *(u16x8*)(dst + 8) = o1;
    }
}

// ---------------- launch ----------------
extern "C" void kernel_launch(void* const* d_in, const int* in_sizes, int n_in,
                              void* d_out, int out_size, void* d_ws, size_t ws_size,
                              hipStream_t stream) {
    const float* x    = (const float*)d_in[0];
    const float* Wqkv = (const float*)d_in[1];
    const float* bqkv = (const float*)d_in[2];
    const float* Wout = (const float*)d_in[3];
    const float* bout = (const float*)d_in[4];
    float* out = (float*)d_out;
    char* ws = (char*)d_ws;

    constexpr size_t SZ_XBF  = (size_t)NPOS * E_ * 2;     // 16 MB (reused for r)
    constexpr size_t SZ_WQBF = (size_t)QKVC * E_ * 2;
    constexpr size_t SZ_WOBF = (size_t)E_ * E_ * 2;
    constexpr size_t SZ_QKVB = (size_t)NPOS * E_ * 2;     // 16 MB each of Q,K,V
    constexpr size_t SZ_SUM  = (size_t)B_ * 512 * 4;      // 8 KB each
    constexpr size_t SZ_V8   = (size_t)NPOS * 8 * 4;      // 512 KB each

    size_t off = 0;
    u16*   xbf   = (u16*)(ws + off);   off += SZ_XBF;
    u16*   wqbf  = (u16*)(ws + off);   off += SZ_WQBF;
    u16*   wobf  = (u16*)(ws + off);   off += SZ_WOBF;
    u16*   Qb    = (u16*)(ws + off);   off += SZ_QKVB;
    u16*   Kb    = (u16*)(ws + off);   off += SZ_QKVB;
    u16*   Vb    = (u16*)(ws + off);   off += SZ_QKVB;
    char*  zbase = ws + off;                       // contiguous zeroed region:
    float* sumq  = (float*)(ws + off); off += SZ_SUM;
    float* sumk  = (float*)(ws + off); off += SZ_SUM;
    float* sumqi = (float*)(ws + off); off += SZ_SUM;
    float* sumko = (float*)(ws + off); off += SZ_SUM;
    float* sm    = (float*)(ws + off); off += 256;
    size_t zlen  = (char*)(ws + off) - zbase;
    float* iv    = (float*)(ws + off); off += SZ_V8;
    float* rowsc = (float*)(ws + off); off += SZ_V8;
    float* wexp  = (float*)(ws + off); off += SZ_V8;
    u16*   rbf   = xbf;   // reuse after GEMM1

    hipMemsetAsync(zbase, 0, zlen, stream);

    cvt_kernel<<<(NPOS * E_ / 4) / 256, 256, 0, stream>>>((const float4*)x, (u16x4*)xbf, NPOS * E_ / 4);
    cvt_kernel<<<(QKVC * E_ / 4) / 256, 256, 0, stream>>>((const float4*)Wqkv, (u16x4*)wqbf, QKVC * E_ / 4);
    cvt_kernel<<<(E_ * E_ / 4) / 256, 256, 0, stream>>>((const float4*)Wout, (u16x4*)wobf, E_ * E_ / 4);

    gemm_qkv<<<dim3(QKVC / 128, NPOS / 128), 256, 0, stream>>>(xbf, wqbf, bqkv, Qb, Kb, Vb, K_);

    sum_qk<<<dim3(B_, 128), 256, 0, stream>>>(Qb, Kb, sumq, sumk);
    fused_io<<<dim3(B_, 128), 256, 0, stream>>>(Qb, Kb, sumq, sumk, iv, sumqi, sumko);
    io2_kernel<<<dim3(B_, 128), 256, 0, stream>>>(Qb, Kb, sumqi, sumko, iv, rowsc, wexp, sm);
    finalize_kernel<<<NPOS / 8, 256, 0, stream>>>(Qb, Kb, Vb, rowsc, wexp, sm, rbf);

    gemm_out<<<dim3(E_ / 128, NPOS / 128), 256, 0, stream>>>(rbf, wobf, bout, out, E_, K_);
}